// Round 6
// baseline (209.994 us; speedup 1.0000x reference)
//
#include <hip/hip_runtime.h>
#include <cmath>

#define T_TOKENS 16384
#define DIM 2048
#define HH 64
#define NG 4
#define EPG 16
#define NE 64
#define NJ 132
#define NJP 144          // padded to 9 n-tiles
#define NT 9
#define NWAVE 8          // waves per block
#define KCHUNK (DIM / NWAVE)     // 256 K per wave
#define KSTEPS (KCHUNK / 32)     // 8
#define TAU 0.02f
#define KEPS 1.5e-3f

typedef __attribute__((ext_vector_type(8))) short bf16x8;
typedef __attribute__((ext_vector_type(4))) float f32x4;

// ws float-offsets
#define WF_FLOATS (64 * NT * 64 * 4)    // fragment-linear bf16 weights, 64 ksteps
#define SUM_OFF WF_FLOATS               // 128 floats: usage, rp
#define CNT_OFF (SUM_OFF + 128)
#define LIST_OFF (CNT_OFF + 4)          // int4 entries (16B aligned)

static __device__ inline unsigned bf16rne(float x) {
    unsigned u = __float_as_uint(x);
    return (u + 0x7FFFu + ((u >> 16) & 1u)) >> 16;
}
static __device__ inline unsigned pk2trunc(float a, float b) {
    return (__float_as_uint(a) >> 16) | (__float_as_uint(b) & 0xFFFF0000u);
}
static __device__ inline bf16x8 packA(float4 a, float4 b) {
    union { unsigned u[4]; bf16x8 v; } r;
    r.u[0] = pk2trunc(a.x, a.y); r.u[1] = pk2trunc(a.z, a.w);
    r.u[2] = pk2trunc(b.x, b.y); r.u[3] = pk2trunc(b.z, b.w);
    return r.v;
}

// Build fragment-linear bf16 weight buffer: [kstep 64][ntile 9][lane 64][16B]
// Block 0 also zeroes the global sums + flag counter.
__global__ void moe_prep(const float* __restrict__ Wg, const float* __restrict__ We,
                         const float* __restrict__ W1, float* __restrict__ ws,
                         float* __restrict__ sums, int* __restrict__ cnt) {
    int bid = blockIdx.x;                 // 576
    int kstep = bid / NT, nt = bid % NT;
    int lane = threadIdx.x;               // 64
    if (bid == 0) {
        sums[lane] = 0.f; sums[64 + lane] = 0.f;
        if (lane == 0) *cnt = 0;
    }
    int row = nt * 16 + (lane & 15);
    int k0 = kstep * 32 + (lane >> 4) * 8;
    const float* src = nullptr;
    if (row < HH)            src = W1 + (size_t)row * DIM;
    else if (row < HH + NG)  src = Wg + (size_t)(row - HH) * DIM;
    else if (row < NJ)       src = We + (size_t)(row - HH - NG) * DIM;
    unsigned r0 = 0, r1 = 0, r2 = 0, r3 = 0;
    if (src) {
        r0 = bf16rne(src[k0 + 0]) | (bf16rne(src[k0 + 1]) << 16);
        r1 = bf16rne(src[k0 + 2]) | (bf16rne(src[k0 + 3]) << 16);
        r2 = bf16rne(src[k0 + 4]) | (bf16rne(src[k0 + 5]) << 16);
        r3 = bf16rne(src[k0 + 6]) | (bf16rne(src[k0 + 7]) << 16);
    }
    ((uint4*)ws)[(size_t)(kstep * NT + nt) * 64 + lane] = make_uint4(r0, r1, r2, r3);
}

// Fused GEMM + epilogue: 1024 blocks x 512 threads; 16 tokens/block;
// wave w computes K-chunk [w*256,(w+1)*256) and atomically adds into the LDS logit tile.
__global__ __launch_bounds__(512, 8) void moe_fused(
    const float* __restrict__ x, const float* __restrict__ wfrag,
    const float* __restrict__ b1, const float* __restrict__ W2,
    const float* __restrict__ b2, const int* __restrict__ minE,
    const int* __restrict__ maxE, float* __restrict__ out,
    float* __restrict__ sums, int* __restrict__ cnt, int4* __restrict__ list) {
    __shared__ float slog[16][145];
    __shared__ float rp_s[16 * 17];
    __shared__ float sc_n1[16], sc_n2[16], sc_u2[16];
    __shared__ int   sc_e1[16], sc_e2[16], sc_g[16];
    __shared__ float s_usage[NE], s_rp[NE];

    const int tid = threadIdx.x;
    const int wave = tid >> 6, lane = tid & 63;
    const int l15 = lane & 15, lq = lane >> 4;
    const int T0 = blockIdx.x * 16;

    for (int i = tid; i < 16 * 145; i += 512) ((float*)slog)[i] = 0.f;
    if (tid < NE) { s_usage[tid] = 0.f; s_rp[tid] = 0.f; }
    __syncthreads();

    const int tokA = T0 + l15;
    const float4* xp = (const float4*)(x + (size_t)tokA * DIM + wave * KCHUNK + lq * 8);
    const bf16x8* wf = (const bf16x8*)wfrag + (size_t)(wave * KSTEPS) * NT * 64 + lane;

    f32x4 acc[NT];
    #pragma unroll
    for (int n = 0; n < NT; ++n) acc[n] = (f32x4){0.f, 0.f, 0.f, 0.f};

    float4 aA0 = xp[0], aA1 = xp[1];
    bf16x8 bA[NT], bB[NT];
    #pragma unroll
    for (int n = 0; n < NT; ++n) bA[n] = wf[n * 64];
    float4 aB0, aB1;

    #pragma unroll 2
    for (int t = 0; t < KSTEPS; t += 2) {
        const int t1 = (t + 1 < KSTEPS) ? t + 1 : t;
        aB0 = xp[t1 * 8]; aB1 = xp[t1 * 8 + 1];
        #pragma unroll
        for (int n = 0; n < NT; ++n) bB[n] = wf[(t1 * NT + n) * 64];
        bf16x8 af = packA(aA0, aA1);
        #pragma unroll
        for (int n = 0; n < NT; ++n)
            acc[n] = __builtin_amdgcn_mfma_f32_16x16x32_bf16(af, bA[n], acc[n], 0, 0, 0);

        const int t2 = (t + 2 < KSTEPS) ? t + 2 : t;
        aA0 = xp[t2 * 8]; aA1 = xp[t2 * 8 + 1];
        #pragma unroll
        for (int n = 0; n < NT; ++n) bA[n] = wf[(t2 * NT + n) * 64];
        af = packA(aB0, aB1);
        #pragma unroll
        for (int n = 0; n < NT; ++n)
            acc[n] = __builtin_amdgcn_mfma_f32_16x16x32_bf16(af, bB[n], acc[n], 0, 0, 0);
    }

    // C/D: col(n-dim) = l15, row(token) = lq*4 + r. Accumulate across waves in LDS.
    #pragma unroll
    for (int n = 0; n < NT; ++n)
        #pragma unroll
        for (int r = 0; r < 4; ++r)
            atomicAdd(&slog[lq * 4 + r][n * 16 + l15], acc[n][r]);
    __syncthreads();

    // per-token epilogue (16 tokens, lanes 0..15 of wave 0)
    if (tid < 16) {
        const int t = tid, tok = T0 + t;
        const float* o = slog[t];

        float z = b2[0];
        #pragma unroll 8
        for (int i = 0; i < HH; ++i) {
            float h = o[i] + b1[i];
            z = fmaf(W2[i], h > 0.f ? h : 0.f, z);
        }
        float c = 1.f / (1.f + expf(-z));
        int mx = maxE[0], mn = minE[0];
        float y = c * (float)mx;
        int k = (int)y; k = k < mn ? mn : (k > mx ? mx : k);
        int kl = (int)(y - KEPS); kl = kl < mn ? mn : (kl > mx ? mx : kl);
        int kh = (int)(y + KEPS); kh = kh < mn ? mn : (kh > mx ? mx : kh);
        bool flagK = (kl != kh);
        float u2 = (k >= 2) ? 1.f : 0.f;

        float gl[NG]; float gm = -INFINITY; int gi = 0;
        #pragma unroll
        for (int g = 0; g < NG; ++g) {
            gl[g] = o[HH + g];
            if (gl[g] > gm) { gm = gl[g]; gi = g; }
        }
        float g2 = -INFINITY;
        #pragma unroll
        for (int g = 0; g < NG; ++g) if (g != gi && gl[g] > g2) g2 = gl[g];
        bool flagG = (gm - g2) < TAU;
        float gsum = 0.f;
        #pragma unroll
        for (int g = 0; g < NG; ++g) gsum += expf(gl[g] - gm);
        float gp = 1.f / gsum;

        float el[EPG];
        #pragma unroll
        for (int j = 0; j < EPG; ++j) el[j] = o[HH + NG + gi * EPG + j];
        float e1 = -INFINITY, e2v = -INFINITY, e3v = -INFINITY; int i1 = 0, i2 = 0;
        #pragma unroll
        for (int j = 0; j < EPG; ++j) {
            float v = el[j];
            if (v > e1)       { e3v = e2v; e2v = e1; i2 = i1; e1 = v; i1 = j; }
            else if (v > e2v) { e3v = e2v; e2v = v; i2 = j; }
            else if (v > e3v) { e3v = v; }
        }
        bool flagE = ((e1 - e2v) < TAU) || (u2 > 0.f && (e2v - e3v) < TAU);

        float ep[EPG]; float es = 0.f;
        #pragma unroll
        for (int j = 0; j < EPG; ++j) { ep[j] = expf(el[j] - e1); es += ep[j]; }
        float inv = 1.f / es;
        #pragma unroll
        for (int j = 0; j < EPG; ++j) ep[j] *= inv;
        float v1 = ep[i1], v2 = ep[i2];
        float denom = v1 + v2 * u2;
        sc_n1[t] = v1 / denom; sc_n2[t] = v2 * u2 / denom; sc_u2[t] = u2;
        sc_e1[t] = gi * EPG + i1; sc_e2[t] = gi * EPG + i2; sc_g[t] = gi;
        #pragma unroll
        for (int j = 0; j < EPG; ++j) rp_s[t * 17 + j] = gp * ep[j];

        if (flagK || flagG || flagE) {
            int p = atomicAdd(cnt, 1);
            int fl = (flagG ? 1 : 0) | (flagE ? 2 : 0) | (flagK ? 4 : 0);
            list[p] = make_int4(tok, fl, (int)u2, 0);
        }
    }
    __syncthreads();

    float* outD = out;
    float* outC = out + (size_t)T_TOKENS * NE;
    float* outR = out + (size_t)2 * T_TOKENS * NE;
    for (int idx = tid; idx < 16 * NE; idx += 512) {
        int t = idx >> 6, e = idx & 63;
        int e1i = sc_e1[t], e2i = sc_e2[t];
        float disp = (e == e1i ? 1.f : 0.f) + (e == e2i ? sc_u2[t] : 0.f);
        float comb = (e == e1i ? sc_n1[t] : 0.f) + (e == e2i ? sc_n2[t] : 0.f);
        float rpv  = ((e >> 4) == sc_g[t]) ? rp_s[t * 17 + (e & 15)] : 0.f;
        size_t ob = (size_t)(T0 + t) * NE + e;
        outD[ob] = disp; outC[ob] = comb; outR[ob] = rpv;
        atomicAdd(&s_usage[e], disp);
        atomicAdd(&s_rp[e], rpv);
    }
    __syncthreads();
    if (tid < NE) {
        atomicAdd(&sums[tid], s_usage[tid]);
        atomicAdd(&sums[NE + tid], s_rp[tid]);
    }
}

// parallel fixup: one block (4 waves) per flagged token
__global__ __launch_bounds__(256, 4) void moe_fix(
    const float* __restrict__ x, const float* __restrict__ Wg,
    const float* __restrict__ We, const float* __restrict__ W1,
    const float* __restrict__ b1, const float* __restrict__ W2,
    const float* __restrict__ b2, const int* __restrict__ minE,
    const int* __restrict__ maxE, float* __restrict__ out,
    float* __restrict__ sums, const int* __restrict__ cnt,
    const int4* __restrict__ list) {
    __shared__ float gl_s[NG];
    __shared__ float h_s[HH];
    __shared__ float el_s[EPG];
    __shared__ float rp_row[EPG];
    __shared__ int   s_gi;
    __shared__ float s_u2, s_gp;
    __shared__ int   s_e1, s_e2;
    __shared__ float s_n1, s_n2;

    const int tid = threadIdx.x;
    const int wave = tid >> 6, lane = tid & 63;
    const int n = *cnt;

    for (int i = blockIdx.x; i < n; i += gridDim.x) {
        const int4 ent = list[i];
        const int tok = ent.x, fl = ent.y;
        const float u2_in = (float)ent.z;

        const float* xrow = x + (size_t)tok * DIM;
        float xr[32];
        #pragma unroll
        for (int m = 0; m < 32; ++m) xr[m] = xrow[lane + m * 64];

        auto dotf = [&](const float* w) -> float {
            float s = 0.f;
            #pragma unroll
            for (int m = 0; m < 32; ++m) s = fmaf(xr[m], w[lane + m * 64], s);
            #pragma unroll
            for (int off = 32; off; off >>= 1) s += __shfl_xor(s, off, 64);
            return s;
        };

        {
            float g = dotf(Wg + (size_t)wave * DIM);
            if (lane == 0) gl_s[wave] = g;
        }
        if (fl & 4) {
            for (int j = wave; j < HH; j += 4) {
                float hv = dotf(W1 + (size_t)j * DIM);
                if (lane == 0) h_s[j] = hv;
            }
        }
        __syncthreads();

        if (tid == 0) {
            float gm = -INFINITY; int gi = 0;
            #pragma unroll
            for (int g = 0; g < NG; ++g)
                if (gl_s[g] > gm) { gm = gl_s[g]; gi = g; }
            float gsum = 0.f;
            #pragma unroll
            for (int g = 0; g < NG; ++g) gsum += expf(gl_s[g] - gm);
            s_gp = 1.f / gsum;
            s_gi = gi;
            float u2 = u2_in;
            if (fl & 4) {
                float z = b2[0];
                for (int j = 0; j < HH; ++j) {
                    float h = h_s[j] + b1[j];
                    z = fmaf(W2[j], h > 0.f ? h : 0.f, z);
                }
                float c = 1.f / (1.f + expf(-z));
                int mx = maxE[0], mn = minE[0];
                int k = (int)(c * (float)mx);
                k = k < mn ? mn : (k > mx ? mx : k);
                u2 = (k >= 2) ? 1.f : 0.f;
            }
            s_u2 = u2;
        }
        __syncthreads();

        const int gi = s_gi;
        for (int j = wave; j < EPG; j += 4) {
            float e = dotf(We + (size_t)(gi * EPG + j) * DIM);
            if (lane == 0) el_s[j] = e;
        }
        __syncthreads();

        if (tid == 0) {
            float e1 = -INFINITY, e2v = -INFINITY; int i1 = 0, i2 = 0;
            #pragma unroll
            for (int j = 0; j < EPG; ++j) {
                float v = el_s[j];
                if (v > e1)       { e2v = e1; i2 = i1; e1 = v; i1 = j; }
                else if (v > e2v) { e2v = v; i2 = j; }
            }
            float es = 0.f;
            #pragma unroll
            for (int j = 0; j < EPG; ++j) {
                float e = expf(el_s[j] - e1);
                rp_row[j] = e;
                es += e;
            }
            float inv = 1.f / es;
            float gp = s_gp;
            #pragma unroll
            for (int j = 0; j < EPG; ++j) rp_row[j] *= inv * gp;
            float v1 = expf(el_s[i1] - e1) * inv;
            float v2 = expf(el_s[i2] - e1) * inv;
            float u2 = s_u2;
            float denom = v1 + v2 * u2;
            s_n1 = v1 / denom; s_n2 = v2 * u2 / denom;
            s_e1 = gi * EPG + i1; s_e2 = gi * EPG + i2;
        }
        __syncthreads();

        if (tid < NE) {
            const int e = tid;
            float u2 = s_u2;
            float newD = (e == s_e1 ? 1.f : 0.f) + (e == s_e2 ? u2 : 0.f);
            float newC = (e == s_e1 ? s_n1 : 0.f) + (e == s_e2 ? s_n2 : 0.f);
            float newR = ((e >> 4) == gi) ? rp_row[e & 15] : 0.f;
            size_t ob = (size_t)tok * NE + e;
            float oldD = out[ob];
            float oldR = out[(size_t)2 * T_TOKENS * NE + ob];
            out[ob] = newD;
            out[(size_t)T_TOKENS * NE + ob] = newC;
            out[(size_t)2 * T_TOKENS * NE + ob] = newR;
            float dD = newD - oldD, dR = newR - oldR;
            if (dD != 0.f) atomicAdd(&sums[e], dD);
            if (dR != 0.f) atomicAdd(&sums[NE + e], dR);
        }
        __syncthreads();
    }
}

__global__ void moe_finalize(const float* __restrict__ sums, float* __restrict__ out) {
    int l = threadIdx.x;
    float v = sums[l] * sums[NE + l];
    #pragma unroll
    for (int off = 32; off; off >>= 1) v += __shfl_down(v, off, 64);
    if (l == 0) {
        float N = (float)T_TOKENS;
        out[(size_t)3 * T_TOKENS * NE] = v * (float)NE / (N * N);
    }
}

extern "C" void kernel_launch(void* const* d_in, const int* in_sizes, int n_in,
                              void* d_out, int out_size, void* d_ws, size_t ws_size,
                              hipStream_t stream) {
    const float* x  = (const float*)d_in[0];
    const float* Wg = (const float*)d_in[1];
    const float* We = (const float*)d_in[2];
    const float* W1 = (const float*)d_in[3];
    const float* b1 = (const float*)d_in[4];
    const float* W2 = (const float*)d_in[5];
    const float* b2 = (const float*)d_in[6];
    const int* minE = (const int*)d_in[7];
    const int* maxE = (const int*)d_in[8];
    float* out = (float*)d_out;
    float* ws  = (float*)d_ws;

    float* wfrag = ws;
    float* sums  = ws + SUM_OFF;
    int*   cnt   = (int*)(ws + CNT_OFF);
    int4*  list  = (int4*)(ws + LIST_OFF);

    moe_prep<<<64 * NT, 64, 0, stream>>>(Wg, We, W1, wfrag, sums, cnt);
    moe_fused<<<T_TOKENS / 16, 512, 0, stream>>>(x, wfrag, b1, W2, b2, minE, maxE,
                                                 out, sums, cnt, list);
    moe_fix<<<2048, 256, 0, stream>>>(x, Wg, We, W1, b1, W2, b2, minE, maxE,
                                      out, sums, cnt, list);
    moe_finalize<<<1, 64, 0, stream>>>(sums, out);
}

// Round 7
// 149.705 us; speedup vs baseline: 1.4027x; 1.4027x over previous
//
#include <hip/hip_runtime.h>
#include <cmath>

#define T_TOKENS 16384
#define DIM 2048
#define HH 64
#define NG 4
#define EPG 16
#define NE 64
#define NJ 132
#define NT 9            // n-tiles of 16 (144 padded)
#define KTOT 64         // 2048 / 32 ksteps
#define TAU 0.02f
#define KEPS 1.5e-3f

typedef __attribute__((ext_vector_type(8))) short bf16x8;
typedef __attribute__((ext_vector_type(4))) float f32x4;

// ws float-offsets
#define WF_FLOATS (64 * NT * 64 * 4)    // fragment-linear bf16 weights, 64 ksteps
#define SUM_OFF WF_FLOATS               // 128 floats: usage, rp
#define CNT_OFF (SUM_OFF + 128)
#define LIST_OFF (CNT_OFF + 4)          // int4 entries (16B aligned)

static __device__ inline unsigned bf16rne(float x) {
    unsigned u = __float_as_uint(x);
    return (u + 0x7FFFu + ((u >> 16) & 1u)) >> 16;
}
static __device__ inline unsigned pk2trunc(float a, float b) {
    return (__float_as_uint(a) >> 16) | (__float_as_uint(b) & 0xFFFF0000u);
}
static __device__ inline bf16x8 packA(float4 a, float4 b) {
    union { unsigned u[4]; bf16x8 v; } r;
    r.u[0] = pk2trunc(a.x, a.y); r.u[1] = pk2trunc(a.z, a.w);
    r.u[2] = pk2trunc(b.x, b.y); r.u[3] = pk2trunc(b.z, b.w);
    return r.v;
}

// Build fragment-linear bf16 weight buffer: [kstep 64][ntile 9][lane 64][16B]
__global__ void moe_prep(const float* __restrict__ Wg, const float* __restrict__ We,
                         const float* __restrict__ W1, float* __restrict__ ws,
                         float* __restrict__ sums, int* __restrict__ cnt) {
    int bid = blockIdx.x;                 // 576
    int kstep = bid / NT, nt = bid % NT;
    int lane = threadIdx.x;               // 64
    if (bid == 0) {
        sums[lane] = 0.f; sums[64 + lane] = 0.f;
        if (lane == 0) *cnt = 0;
    }
    int row = nt * 16 + (lane & 15);
    int k0 = kstep * 32 + (lane >> 4) * 8;
    const float* src = nullptr;
    if (row < HH)            src = W1 + (size_t)row * DIM;
    else if (row < HH + NG)  src = Wg + (size_t)(row - HH) * DIM;
    else if (row < NJ)       src = We + (size_t)(row - HH - NG) * DIM;
    unsigned r0 = 0, r1 = 0, r2 = 0, r3 = 0;
    if (src) {
        r0 = bf16rne(src[k0 + 0]) | (bf16rne(src[k0 + 1]) << 16);
        r1 = bf16rne(src[k0 + 2]) | (bf16rne(src[k0 + 3]) << 16);
        r2 = bf16rne(src[k0 + 4]) | (bf16rne(src[k0 + 5]) << 16);
        r3 = bf16rne(src[k0 + 6]) | (bf16rne(src[k0 + 7]) << 16);
    }
    ((uint4*)ws)[(size_t)(kstep * NT + nt) * 64 + lane] = make_uint4(r0, r1, r2, r3);
}

// Fused kernel: 1024 blocks x 256 threads, 16 tokens/block.
// Wave w computes n-tiles {w, w+4, 8} over the FULL K (no reduction needed).
// 4-deep x prefetch ring + 2-deep weight double buffer, fully unrolled k-loop.
__global__ __launch_bounds__(256, 4) void moe_fused(
    const float* __restrict__ x, const float* __restrict__ wfrag,
    const float* __restrict__ b1, const float* __restrict__ W2,
    const float* __restrict__ b2, const int* __restrict__ minE,
    const int* __restrict__ maxE, float* __restrict__ out,
    float* __restrict__ sums, int* __restrict__ cnt, int4* __restrict__ list) {
    __shared__ float slog[16][145];
    __shared__ float rp_s[16 * 17];
    __shared__ float sc_n1[16], sc_n2[16], sc_u2[16];
    __shared__ int   sc_e1[16], sc_e2[16];
    __shared__ float s_usage[NE], s_rp[NE];

    const int tid = threadIdx.x;
    const int wave = tid >> 6, lane = tid & 63;
    const int l15 = lane & 15, lq = lane >> 4;
    const int T0 = blockIdx.x * 16;

    if (tid < NE) { s_usage[tid] = 0.f; s_rp[tid] = 0.f; }

    const int ntA = wave, ntB = wave + 4, ntC = 8;
    const float4* xp = (const float4*)(x + (size_t)(T0 + l15) * DIM + lq * 8);
    const bf16x8* wf = (const bf16x8*)wfrag + lane;

    f32x4 accA = (f32x4){0.f,0.f,0.f,0.f};
    f32x4 accB = (f32x4){0.f,0.f,0.f,0.f};
    f32x4 accC = (f32x4){0.f,0.f,0.f,0.f};

    float4 xa[4], xb[4];
    bf16x8 wA[2], wB[2], wC[2];
    #pragma unroll
    for (int p = 0; p < 4; ++p) { xa[p] = xp[p * 8]; xb[p] = xp[p * 8 + 1]; }
    #pragma unroll
    for (int p = 0; p < 2; ++p) {
        wA[p] = wf[(p * NT + ntA) * 64];
        wB[p] = wf[(p * NT + ntB) * 64];
        wC[p] = wf[(p * NT + ntC) * 64];
    }

    #pragma unroll
    for (int t = 0; t < KTOT; ++t) {
        bf16x8 af = packA(xa[t & 3], xb[t & 3]);
        if (t + 4 < KTOT) {
            xa[t & 3] = xp[(t + 4) * 8];
            xb[t & 3] = xp[(t + 4) * 8 + 1];
        }
        accA = __builtin_amdgcn_mfma_f32_16x16x32_bf16(af, wA[t & 1], accA, 0, 0, 0);
        accB = __builtin_amdgcn_mfma_f32_16x16x32_bf16(af, wB[t & 1], accB, 0, 0, 0);
        accC = __builtin_amdgcn_mfma_f32_16x16x32_bf16(af, wC[t & 1], accC, 0, 0, 0);
        if (t + 2 < KTOT) {
            wA[t & 1] = wf[((t + 2) * NT + ntA) * 64];
            wB[t & 1] = wf[((t + 2) * NT + ntB) * 64];
            wC[t & 1] = wf[((t + 2) * NT + ntC) * 64];
        }
    }

    // C/D: col = l15 (n within tile), row(token) = lq*4 + r
    #pragma unroll
    for (int r = 0; r < 4; ++r) {
        slog[lq * 4 + r][ntA * 16 + l15] = accA[r];
        slog[lq * 4 + r][ntB * 16 + l15] = accB[r];
        if (wave == 0) slog[lq * 4 + r][ntC * 16 + l15] = accC[r];
    }
    __syncthreads();

    // parallel epilogue: 16 groups of 16 lanes; group g handles token g
    {
        const int t = tid >> 4;       // token within block
        const int q = tid & 15;       // lane within group (aligned to wave quarters)
        const int tok = T0 + t;
        const float* o = slog[t];

        // complexity MLP: each lane 4 terms, shfl-16 reduce
        float4 b1v = ((const float4*)b1)[q];
        float4 w2v = ((const float4*)W2)[q];
        float part;
        {
            float h0 = o[q * 4 + 0] + b1v.x; h0 = h0 > 0.f ? h0 : 0.f;
            float h1 = o[q * 4 + 1] + b1v.y; h1 = h1 > 0.f ? h1 : 0.f;
            float h2 = o[q * 4 + 2] + b1v.z; h2 = h2 > 0.f ? h2 : 0.f;
            float h3 = o[q * 4 + 3] + b1v.w; h3 = h3 > 0.f ? h3 : 0.f;
            part = h0 * w2v.x + h1 * w2v.y + h2 * w2v.z + h3 * w2v.w;
        }
        #pragma unroll
        for (int off = 8; off; off >>= 1) part += __shfl_xor(part, off, 16);
        float z = b2[0] + part;
        float c = 1.f / (1.f + expf(-z));
        int mx = maxE[0], mn = minE[0];
        float y = c * (float)mx;
        int k = (int)y; k = k < mn ? mn : (k > mx ? mx : k);
        int kl = (int)(y - KEPS); kl = kl < mn ? mn : (kl > mx ? mx : kl);
        int kh = (int)(y + KEPS); kh = kh < mn ? mn : (kh > mx ? mx : kh);
        bool flagK = (kl != kh);
        float u2 = (k >= 2) ? 1.f : 0.f;

        // group softmax/argmax (redundant per lane; LDS broadcast)
        float gl0 = o[HH + 0], gl1 = o[HH + 1], gl2 = o[HH + 2], gl3 = o[HH + 3];
        float gm = gl0; int gi = 0;
        if (gl1 > gm) { gm = gl1; gi = 1; }
        if (gl2 > gm) { gm = gl2; gi = 2; }
        if (gl3 > gm) { gm = gl3; gi = 3; }
        float g2 = -INFINITY;
        if (gi != 0 && gl0 > g2) g2 = gl0;
        if (gi != 1 && gl1 > g2) g2 = gl1;
        if (gi != 2 && gl2 > g2) g2 = gl2;
        if (gi != 3 && gl3 > g2) g2 = gl3;
        bool flagG = (gm - g2) < TAU;
        float gsum = expf(gl0 - gm) + expf(gl1 - gm) + expf(gl2 - gm) + expf(gl3 - gm);
        float gp = 1.f / gsum;

        // expert softmax + top-2, lane-parallel (lane q = expert q of chosen group)
        float el = o[HH + NG + gi * EPG + q];
        float v1v = el; int i1 = q;
        #pragma unroll
        for (int off = 8; off; off >>= 1) {
            float ov = __shfl_xor(v1v, off, 16);
            int   oi = __shfl_xor(i1, off, 16);
            if (ov > v1v || (ov == v1v && oi < i1)) { v1v = ov; i1 = oi; }
        }
        float m2 = (q == i1) ? -INFINITY : el; int i2 = q;
        float v2v = m2;
        #pragma unroll
        for (int off = 8; off; off >>= 1) {
            float ov = __shfl_xor(v2v, off, 16);
            int   oi = __shfl_xor(i2, off, 16);
            if (ov > v2v || (ov == v2v && oi < i2)) { v2v = ov; i2 = oi; }
        }
        float m3 = (q == i1 || q == i2) ? -INFINITY : el;
        float e3v = m3;
        #pragma unroll
        for (int off = 8; off; off >>= 1)
            e3v = fmaxf(e3v, __shfl_xor(e3v, off, 16));
        bool flagE = ((v1v - v2v) < TAU) || (u2 > 0.f && (v2v - e3v) < TAU);

        float ep = expf(el - v1v);
        float es = ep;
        #pragma unroll
        for (int off = 8; off; off >>= 1) es += __shfl_xor(es, off, 16);
        float inv = 1.f / es;
        rp_s[t * 17 + q] = gp * ep * inv;

        if (q == 0) {
            float v1p = inv;                       // exp(0)*inv
            float v2p = expf(v2v - v1v) * inv;
            float denom = v1p + v2p * u2;
            sc_n1[t] = v1p / denom; sc_n2[t] = v2p * u2 / denom; sc_u2[t] = u2;
            sc_e1[t] = gi * EPG + i1; sc_e2[t] = gi * EPG + i2;
            // stash group in high bits of sc_e1? keep separate via rp row: store gi in sc_e2 high
            if (flagK || flagG || flagE) {
                int p = atomicAdd(cnt, 1);
                int fl = (flagG ? 1 : 0) | (flagE ? 2 : 0) | (flagK ? 4 : 0);
                list[p] = make_int4(tok, fl, (int)u2, 0);
            }
        }
    }
    __syncthreads();

    float* outD = out;
    float* outC = out + (size_t)T_TOKENS * NE;
    float* outR = out + (size_t)2 * T_TOKENS * NE;
    for (int idx = tid; idx < 16 * NE; idx += 256) {
        int t = idx >> 6, e = idx & 63;
        int e1i = sc_e1[t], e2i = sc_e2[t];
        int gi = e1i >> 4;
        float disp = (e == e1i ? 1.f : 0.f) + (e == e2i ? sc_u2[t] : 0.f);
        float comb = (e == e1i ? sc_n1[t] : 0.f) + (e == e2i ? sc_n2[t] : 0.f);
        float rpv  = ((e >> 4) == gi) ? rp_s[t * 17 + (e & 15)] : 0.f;
        size_t ob = (size_t)(T0 + t) * NE + e;
        outD[ob] = disp; outC[ob] = comb; outR[ob] = rpv;
        atomicAdd(&s_usage[e], disp);
        atomicAdd(&s_rp[e], rpv);
    }
    __syncthreads();
    if (tid < NE) {
        atomicAdd(&sums[tid], s_usage[tid]);
        atomicAdd(&sums[NE + tid], s_rp[tid]);
    }
}

// parallel fixup: one block (4 waves) per flagged token
__global__ __launch_bounds__(256, 4) void moe_fix(
    const float* __restrict__ x, const float* __restrict__ Wg,
    const float* __restrict__ We, const float* __restrict__ W1,
    const float* __restrict__ b1, const float* __restrict__ W2,
    const float* __restrict__ b2, const int* __restrict__ minE,
    const int* __restrict__ maxE, float* __restrict__ out,
    float* __restrict__ sums, const int* __restrict__ cnt,
    const int4* __restrict__ list) {
    __shared__ float gl_s[NG];
    __shared__ float h_s[HH];
    __shared__ float el_s[EPG];
    __shared__ float rp_row[EPG];
    __shared__ int   s_gi;
    __shared__ float s_u2, s_gp;
    __shared__ int   s_e1, s_e2;
    __shared__ float s_n1, s_n2;

    const int tid = threadIdx.x;
    const int wave = tid >> 6, lane = tid & 63;
    const int n = *cnt;

    for (int i = blockIdx.x; i < n; i += gridDim.x) {
        const int4 ent = list[i];
        const int tok = ent.x, fl = ent.y;
        const float u2_in = (float)ent.z;

        const float* xrow = x + (size_t)tok * DIM;
        float xr[32];
        #pragma unroll
        for (int m = 0; m < 32; ++m) xr[m] = xrow[lane + m * 64];

        auto dotf = [&](const float* w) -> float {
            float s = 0.f;
            #pragma unroll
            for (int m = 0; m < 32; ++m) s = fmaf(xr[m], w[lane + m * 64], s);
            #pragma unroll
            for (int off = 32; off; off >>= 1) s += __shfl_xor(s, off, 64);
            return s;
        };

        {
            float g = dotf(Wg + (size_t)wave * DIM);
            if (lane == 0) gl_s[wave] = g;
        }
        if (fl & 4) {
            for (int j = wave; j < HH; j += 4) {
                float hv = dotf(W1 + (size_t)j * DIM);
                if (lane == 0) h_s[j] = hv;
            }
        }
        __syncthreads();

        if (tid == 0) {
            float gm = -INFINITY; int gi = 0;
            #pragma unroll
            for (int g = 0; g < NG; ++g)
                if (gl_s[g] > gm) { gm = gl_s[g]; gi = g; }
            float gsum = 0.f;
            #pragma unroll
            for (int g = 0; g < NG; ++g) gsum += expf(gl_s[g] - gm);
            s_gp = 1.f / gsum;
            s_gi = gi;
            float u2 = u2_in;
            if (fl & 4) {
                float z = b2[0];
                for (int j = 0; j < HH; ++j) {
                    float h = h_s[j] + b1[j];
                    z = fmaf(W2[j], h > 0.f ? h : 0.f, z);
                }
                float c = 1.f / (1.f + expf(-z));
                int mx = maxE[0], mn = minE[0];
                int k = (int)(c * (float)mx);
                k = k < mn ? mn : (k > mx ? mx : k);
                u2 = (k >= 2) ? 1.f : 0.f;
            }
            s_u2 = u2;
        }
        __syncthreads();

        const int gi = s_gi;
        for (int j = wave; j < EPG; j += 4) {
            float e = dotf(We + (size_t)(gi * EPG + j) * DIM);
            if (lane == 0) el_s[j] = e;
        }
        __syncthreads();

        if (tid == 0) {
            float e1 = -INFINITY, e2v = -INFINITY; int i1 = 0, i2 = 0;
            #pragma unroll
            for (int j = 0; j < EPG; ++j) {
                float v = el_s[j];
                if (v > e1)       { e2v = e1; i2 = i1; e1 = v; i1 = j; }
                else if (v > e2v) { e2v = v; i2 = j; }
            }
            float es = 0.f;
            #pragma unroll
            for (int j = 0; j < EPG; ++j) {
                float e = expf(el_s[j] - e1);
                rp_row[j] = e;
                es += e;
            }
            float inv = 1.f / es;
            float gp = s_gp;
            #pragma unroll
            for (int j = 0; j < EPG; ++j) rp_row[j] *= inv * gp;
            float v1 = expf(el_s[i1] - e1) * inv;
            float v2 = expf(el_s[i2] - e1) * inv;
            float u2 = s_u2;
            float denom = v1 + v2 * u2;
            s_n1 = v1 / denom; s_n2 = v2 * u2 / denom;
            s_e1 = gi * EPG + i1; s_e2 = gi * EPG + i2;
        }
        __syncthreads();

        if (tid < NE) {
            const int e = tid;
            float u2 = s_u2;
            float newD = (e == s_e1 ? 1.f : 0.f) + (e == s_e2 ? u2 : 0.f);
            float newC = (e == s_e1 ? s_n1 : 0.f) + (e == s_e2 ? s_n2 : 0.f);
            float newR = ((e >> 4) == gi) ? rp_row[e & 15] : 0.f;
            size_t ob = (size_t)tok * NE + e;
            float oldD = out[ob];
            float oldR = out[(size_t)2 * T_TOKENS * NE + ob];
            out[ob] = newD;
            out[(size_t)T_TOKENS * NE + ob] = newC;
            out[(size_t)2 * T_TOKENS * NE + ob] = newR;
            float dD = newD - oldD, dR = newR - oldR;
            if (dD != 0.f) atomicAdd(&sums[e], dD);
            if (dR != 0.f) atomicAdd(&sums[NE + e], dR);
        }
        __syncthreads();
    }
}

__global__ void moe_finalize(const float* __restrict__ sums, float* __restrict__ out) {
    int l = threadIdx.x;
    float v = sums[l] * sums[NE + l];
    #pragma unroll
    for (int off = 32; off; off >>= 1) v += __shfl_down(v, off, 64);
    if (l == 0) {
        float N = (float)T_TOKENS;
        out[(size_t)3 * T_TOKENS * NE] = v * (float)NE / (N * N);
    }
}

extern "C" void kernel_launch(void* const* d_in, const int* in_sizes, int n_in,
                              void* d_out, int out_size, void* d_ws, size_t ws_size,
                              hipStream_t stream) {
    const float* x  = (const float*)d_in[0];
    const float* Wg = (const float*)d_in[1];
    const float* We = (const float*)d_in[2];
    const float* W1 = (const float*)d_in[3];
    const float* b1 = (const float*)d_in[4];
    const float* W2 = (const float*)d_in[5];
    const float* b2 = (const float*)d_in[6];
    const int* minE = (const int*)d_in[7];
    const int* maxE = (const int*)d_in[8];
    float* out = (float*)d_out;
    float* ws  = (float*)d_ws;

    float* wfrag = ws;
    float* sums  = ws + SUM_OFF;
    int*   cnt   = (int*)(ws + CNT_OFF);
    int4*  list  = (int4*)(ws + LIST_OFF);

    moe_prep<<<64 * NT, 64, 0, stream>>>(Wg, We, W1, wfrag, sums, cnt);
    moe_fused<<<T_TOKENS / 16, 256, 0, stream>>>(x, wfrag, b1, W2, b2, minE, maxE,
                                                 out, sums, cnt, list);
    moe_fix<<<2048, 256, 0, stream>>>(x, Wg, We, W1, b1, W2, b2, minE, maxE,
                                      out, sums, cnt, list);
    moe_finalize<<<1, 64, 0, stream>>>(sums, out);
}

// Round 8
// 113.680 us; speedup vs baseline: 1.8472x; 1.3169x over previous
//
#include <hip/hip_runtime.h>
#include <cmath>

#define T_TOKENS 16384
#define DIM 2048
#define HH 64
#define NG 4
#define EPG 16
#define NE 64
#define NJ 132
#define NT 9            // n-tiles of 16 (144 padded)
#define BM 32           // tokens per block
#define BK 64           // k per iteration (2 ksteps of 32)
#define NITER (DIM / BK)    // 32
#define TAU 0.02f
#define KEPS 1.5e-3f

typedef __attribute__((ext_vector_type(8))) short bf16x8;
typedef __attribute__((ext_vector_type(4))) float f32x4;

// ws float-offsets
#define WF_FLOATS (64 * NT * 64 * 4)    // fragment-linear bf16 weights, 64 ksteps
#define SUM_OFF WF_FLOATS               // 128 floats: usage, rp
#define CNT_OFF (SUM_OFF + 128)
#define LIST_OFF (CNT_OFF + 4)          // int4 entries (16B aligned)

static __device__ inline unsigned bf16rne(float x) {
    unsigned u = __float_as_uint(x);
    return (u + 0x7FFFu + ((u >> 16) & 1u)) >> 16;
}
static __device__ inline unsigned pk2trunc(float a, float b) {
    return (__float_as_uint(a) >> 16) | (__float_as_uint(b) & 0xFFFF0000u);
}

// Build fragment-linear bf16 weight buffer: [kstep 64][ntile 9][lane 64][16B]
__global__ void moe_prep(const float* __restrict__ Wg, const float* __restrict__ We,
                         const float* __restrict__ W1, float* __restrict__ ws,
                         float* __restrict__ sums, int* __restrict__ cnt) {
    int bid = blockIdx.x;                 // 576
    int kstep = bid / NT, nt = bid % NT;
    int lane = threadIdx.x;               // 64
    if (bid == 0) {
        sums[lane] = 0.f; sums[64 + lane] = 0.f;
        if (lane == 0) *cnt = 0;
    }
    int row = nt * 16 + (lane & 15);
    int k0 = kstep * 32 + (lane >> 4) * 8;
    const float* src = nullptr;
    if (row < HH)            src = W1 + (size_t)row * DIM;
    else if (row < HH + NG)  src = Wg + (size_t)(row - HH) * DIM;
    else if (row < NJ)       src = We + (size_t)(row - HH - NG) * DIM;
    unsigned r0 = 0, r1 = 0, r2 = 0, r3 = 0;
    if (src) {
        r0 = bf16rne(src[k0 + 0]) | (bf16rne(src[k0 + 1]) << 16);
        r1 = bf16rne(src[k0 + 2]) | (bf16rne(src[k0 + 3]) << 16);
        r2 = bf16rne(src[k0 + 4]) | (bf16rne(src[k0 + 5]) << 16);
        r3 = bf16rne(src[k0 + 6]) | (bf16rne(src[k0 + 7]) << 16);
    }
    ((uint4*)ws)[(size_t)(kstep * NT + nt) * 64 + lane] = make_uint4(r0, r1, r2, r3);
}

// Fused staged GEMM + epilogue: 512 blocks x 512 threads (8 waves), 32 tokens/block.
// Double-buffered LDS; per iter: issue next loads -> MFMA on cur -> write next -> barrier.
// Wave w: mhalf = w&1 (16 tokens), g = w>>1: n-tiles {g, g+4, +8 if g==0} -> exact cover.
__global__ __launch_bounds__(512, 4) void moe_fused(
    const float* __restrict__ x, const float* __restrict__ wfrag,
    const float* __restrict__ b1, const float* __restrict__ W2,
    const float* __restrict__ b2, const int* __restrict__ minE,
    const int* __restrict__ maxE, float* __restrict__ out,
    float* __restrict__ sums, int* __restrict__ cnt, int4* __restrict__ list) {
    __shared__ uint4 xs[2][4][64];       // [buf][mtile*2+ks][lane]   8 KB
    __shared__ uint4 wsd[2][18][64];     // [buf][ks*9+nt][lane]      36 KB
    __shared__ float slog[BM][145];      // logits tile               18.5 KB
    __shared__ float rp_s[BM * 17];
    __shared__ float sc_n1[BM], sc_n2[BM], sc_u2[BM];
    __shared__ int   sc_e1[BM], sc_e2[BM];
    __shared__ float s_usage[NE], s_rp[NE];

    const int tid = threadIdx.x;          // 0..511
    const int wave = tid >> 6, lane = tid & 63;
    const int l15 = lane & 15, lq = lane >> 4;
    const int T0 = blockIdx.x * BM;

    if (tid < NE) { s_usage[tid] = 0.f; s_rp[tid] = 0.f; }

    // staging role: thread covers token stok, float4 kq of each 64-k slab
    const int stok = tid >> 4;            // 0..31
    const int kq   = tid & 15;            // 0..15
    const float* xg = x + (size_t)(T0 + stok) * DIM + kq * 4;
    const int xcell = ((stok >> 4) * 2 + (kq >> 3)) * 64 + ((kq & 7) >> 1) * 16 + (stok & 15);
    const int xhalf = kq & 1;
    const uint4* wg = (const uint4*)wfrag;

    // compute role
    const int mhalf = wave & 1, g = wave >> 1;
    const int nt0 = g, nt1 = g + 4;       // + tile 8 if g==0
    const bool has3 = (g == 0);

    f32x4 acc0 = (f32x4){0.f,0.f,0.f,0.f};
    f32x4 acc1 = (f32x4){0.f,0.f,0.f,0.f};
    f32x4 acc2 = (f32x4){0.f,0.f,0.f,0.f};

    // prologue: stage iter 0 into buf 0
    {
        float4 xv = *(const float4*)xg;
        uint4 w0 = wg[tid];
        uint4 w1 = wg[512 + tid];
        uint4 w2 = make_uint4(0,0,0,0);
        if (tid < 128) w2 = wg[1024 + tid];
        ((uint2*)&xs[0][0][0])[xcell * 2 + xhalf] = make_uint2(pk2trunc(xv.x, xv.y), pk2trunc(xv.z, xv.w));
        uint4* wd = &wsd[0][0][0];
        wd[tid] = w0; wd[512 + tid] = w1;
        if (tid < 128) wd[1024 + tid] = w2;
        __syncthreads();
    }

    for (int it = 0; it < NITER; ++it) {
        const int cur = it & 1;
        const bool more = (it + 1 < NITER);
        float4 xv;
        uint4 w0, w1, w2;
        if (more) {   // issue next-iter loads early (hide under MFMA)
            xv = *(const float4*)(xg + (it + 1) * BK);
            const uint4* wslab = wg + (size_t)(it + 1) * 1152;
            w0 = wslab[tid];
            w1 = wslab[512 + tid];
            if (tid < 128) w2 = wslab[1024 + tid];
        }
        // compute on cur buffer
        {
            const uint4* xb = &xs[cur][mhalf * 2][0];
            const uint4* wb = &wsd[cur][0][0];
            #pragma unroll
            for (int ks = 0; ks < 2; ++ks) {
                bf16x8 af = *(const bf16x8*)&xb[ks * 64 + lane];
                bf16x8 b0 = *(const bf16x8*)&wb[(ks * 9 + nt0) * 64 + lane];
                bf16x8 b1v = *(const bf16x8*)&wb[(ks * 9 + nt1) * 64 + lane];
                acc0 = __builtin_amdgcn_mfma_f32_16x16x32_bf16(af, b0, acc0, 0, 0, 0);
                acc1 = __builtin_amdgcn_mfma_f32_16x16x32_bf16(af, b1v, acc1, 0, 0, 0);
                if (has3) {
                    bf16x8 b2v = *(const bf16x8*)&wb[(ks * 9 + 8) * 64 + lane];
                    acc2 = __builtin_amdgcn_mfma_f32_16x16x32_bf16(af, b2v, acc2, 0, 0, 0);
                }
            }
        }
        if (more) {   // write next buffer (waitcnt folds here, after compute)
            const int nxt = cur ^ 1;
            ((uint2*)&xs[nxt][0][0])[xcell * 2 + xhalf] = make_uint2(pk2trunc(xv.x, xv.y), pk2trunc(xv.z, xv.w));
            uint4* wd = &wsd[nxt][0][0];
            wd[tid] = w0; wd[512 + tid] = w1;
            if (tid < 128) wd[1024 + tid] = w2;
        }
        __syncthreads();
    }

    // dump accumulators: row(token) = mhalf*16 + lq*4 + r, col = tile*16 + l15
    #pragma unroll
    for (int r = 0; r < 4; ++r) {
        const int row = mhalf * 16 + lq * 4 + r;
        slog[row][nt0 * 16 + l15] = acc0[r];
        slog[row][nt1 * 16 + l15] = acc1[r];
        if (has3) slog[row][8 * 16 + l15] = acc2[r];
    }
    __syncthreads();

    // parallel epilogue: 32 groups of 16 lanes; group t handles token t
    {
        const int t = tid >> 4;       // 0..31
        const int q = tid & 15;
        const int tok = T0 + t;
        const float* o = slog[t];

        float4 b1v = ((const float4*)b1)[q];
        float4 w2v = ((const float4*)W2)[q];
        float part;
        {
            float h0 = o[q * 4 + 0] + b1v.x; h0 = h0 > 0.f ? h0 : 0.f;
            float h1 = o[q * 4 + 1] + b1v.y; h1 = h1 > 0.f ? h1 : 0.f;
            float h2 = o[q * 4 + 2] + b1v.z; h2 = h2 > 0.f ? h2 : 0.f;
            float h3 = o[q * 4 + 3] + b1v.w; h3 = h3 > 0.f ? h3 : 0.f;
            part = h0 * w2v.x + h1 * w2v.y + h2 * w2v.z + h3 * w2v.w;
        }
        #pragma unroll
        for (int off = 8; off; off >>= 1) part += __shfl_xor(part, off, 16);
        float z = b2[0] + part;
        float c = 1.f / (1.f + expf(-z));
        int mx = maxE[0], mn = minE[0];
        float y = c * (float)mx;
        int k = (int)y; k = k < mn ? mn : (k > mx ? mx : k);
        int kl = (int)(y - KEPS); kl = kl < mn ? mn : (kl > mx ? mx : kl);
        int kh = (int)(y + KEPS); kh = kh < mn ? mn : (kh > mx ? mx : kh);
        bool flagK = (kl != kh);
        float u2 = (k >= 2) ? 1.f : 0.f;

        float gl0 = o[HH + 0], gl1 = o[HH + 1], gl2 = o[HH + 2], gl3 = o[HH + 3];
        float gm = gl0; int gi = 0;
        if (gl1 > gm) { gm = gl1; gi = 1; }
        if (gl2 > gm) { gm = gl2; gi = 2; }
        if (gl3 > gm) { gm = gl3; gi = 3; }
        float g2 = -INFINITY;
        if (gi != 0 && gl0 > g2) g2 = gl0;
        if (gi != 1 && gl1 > g2) g2 = gl1;
        if (gi != 2 && gl2 > g2) g2 = gl2;
        if (gi != 3 && gl3 > g2) g2 = gl3;
        bool flagG = (gm - g2) < TAU;
        float gsum = expf(gl0 - gm) + expf(gl1 - gm) + expf(gl2 - gm) + expf(gl3 - gm);
        float gp = 1.f / gsum;

        float el = o[HH + NG + gi * EPG + q];
        float v1v = el; int i1 = q;
        #pragma unroll
        for (int off = 8; off; off >>= 1) {
            float ov = __shfl_xor(v1v, off, 16);
            int   oi = __shfl_xor(i1, off, 16);
            if (ov > v1v || (ov == v1v && oi < i1)) { v1v = ov; i1 = oi; }
        }
        float v2v = (q == i1) ? -INFINITY : el; int i2 = q;
        #pragma unroll
        for (int off = 8; off; off >>= 1) {
            float ov = __shfl_xor(v2v, off, 16);
            int   oi = __shfl_xor(i2, off, 16);
            if (ov > v2v || (ov == v2v && oi < i2)) { v2v = ov; i2 = oi; }
        }
        float e3v = (q == i1 || q == i2) ? -INFINITY : el;
        #pragma unroll
        for (int off = 8; off; off >>= 1)
            e3v = fmaxf(e3v, __shfl_xor(e3v, off, 16));
        bool flagE = ((v1v - v2v) < TAU) || (u2 > 0.f && (v2v - e3v) < TAU);

        float ep = expf(el - v1v);
        float es = ep;
        #pragma unroll
        for (int off = 8; off; off >>= 1) es += __shfl_xor(es, off, 16);
        float inv = 1.f / es;
        rp_s[t * 17 + q] = gp * ep * inv;

        if (q == 0) {
            float v1p = inv;
            float v2p = expf(v2v - v1v) * inv;
            float denom = v1p + v2p * u2;
            sc_n1[t] = v1p / denom; sc_n2[t] = v2p * u2 / denom; sc_u2[t] = u2;
            sc_e1[t] = gi * EPG + i1; sc_e2[t] = gi * EPG + i2;
            if (flagK || flagG || flagE) {
                int p = atomicAdd(cnt, 1);
                int fl = (flagG ? 1 : 0) | (flagE ? 2 : 0) | (flagK ? 4 : 0);
                list[p] = make_int4(tok, fl, (int)u2, 0);
            }
        }
    }
    __syncthreads();

    float* outD = out;
    float* outC = out + (size_t)T_TOKENS * NE;
    float* outR = out + (size_t)2 * T_TOKENS * NE;
    for (int idx = tid; idx < BM * NE; idx += 512) {
        int t = idx >> 6, e = idx & 63;
        int e1i = sc_e1[t], e2i = sc_e2[t];
        int gi = e1i >> 4;
        float disp = (e == e1i ? 1.f : 0.f) + (e == e2i ? sc_u2[t] : 0.f);
        float comb = (e == e1i ? sc_n1[t] : 0.f) + (e == e2i ? sc_n2[t] : 0.f);
        float rpv  = ((e >> 4) == gi) ? rp_s[t * 17 + (e & 15)] : 0.f;
        size_t ob = (size_t)(T0 + t) * NE + e;
        outD[ob] = disp; outC[ob] = comb; outR[ob] = rpv;
        atomicAdd(&s_usage[e], disp);
        atomicAdd(&s_rp[e], rpv);
    }
    __syncthreads();
    if (tid < NE) {
        atomicAdd(&sums[tid], s_usage[tid]);
        atomicAdd(&sums[NE + tid], s_rp[tid]);
    }
}

// parallel fixup: one block (4 waves) per flagged token
__global__ __launch_bounds__(256, 4) void moe_fix(
    const float* __restrict__ x, const float* __restrict__ Wg,
    const float* __restrict__ We, const float* __restrict__ W1,
    const float* __restrict__ b1, const float* __restrict__ W2,
    const float* __restrict__ b2, const int* __restrict__ minE,
    const int* __restrict__ maxE, float* __restrict__ out,
    float* __restrict__ sums, const int* __restrict__ cnt,
    const int4* __restrict__ list) {
    __shared__ float gl_s[NG];
    __shared__ float h_s[HH];
    __shared__ float el_s[EPG];
    __shared__ float rp_row[EPG];
    __shared__ int   s_gi;
    __shared__ float s_u2, s_gp;
    __shared__ int   s_e1, s_e2;
    __shared__ float s_n1, s_n2;

    const int tid = threadIdx.x;
    const int wave = tid >> 6, lane = tid & 63;
    const int n = *cnt;

    for (int i = blockIdx.x; i < n; i += gridDim.x) {
        const int4 ent = list[i];
        const int tok = ent.x, fl = ent.y;
        const float u2_in = (float)ent.z;

        const float* xrow = x + (size_t)tok * DIM;
        float xr[32];
        #pragma unroll
        for (int m = 0; m < 32; ++m) xr[m] = xrow[lane + m * 64];

        auto dotf = [&](const float* w) -> float {
            float s = 0.f;
            #pragma unroll
            for (int m = 0; m < 32; ++m) s = fmaf(xr[m], w[lane + m * 64], s);
            #pragma unroll
            for (int off = 32; off; off >>= 1) s += __shfl_xor(s, off, 64);
            return s;
        };

        {
            float g = dotf(Wg + (size_t)wave * DIM);
            if (lane == 0) gl_s[wave] = g;
        }
        if (fl & 4) {
            for (int j = wave; j < HH; j += 4) {
                float hv = dotf(W1 + (size_t)j * DIM);
                if (lane == 0) h_s[j] = hv;
            }
        }
        __syncthreads();

        if (tid == 0) {
            float gm = -INFINITY; int gi = 0;
            #pragma unroll
            for (int g = 0; g < NG; ++g)
                if (gl_s[g] > gm) { gm = gl_s[g]; gi = g; }
            float gsum = 0.f;
            #pragma unroll
            for (int g = 0; g < NG; ++g) gsum += expf(gl_s[g] - gm);
            s_gp = 1.f / gsum;
            s_gi = gi;
            float u2 = u2_in;
            if (fl & 4) {
                float z = b2[0];
                for (int j = 0; j < HH; ++j) {
                    float h = h_s[j] + b1[j];
                    z = fmaf(W2[j], h > 0.f ? h : 0.f, z);
                }
                float c = 1.f / (1.f + expf(-z));
                int mx = maxE[0], mn = minE[0];
                int k = (int)(c * (float)mx);
                k = k < mn ? mn : (k > mx ? mx : k);
                u2 = (k >= 2) ? 1.f : 0.f;
            }
            s_u2 = u2;
        }
        __syncthreads();

        const int gi = s_gi;
        for (int j = wave; j < EPG; j += 4) {
            float e = dotf(We + (size_t)(gi * EPG + j) * DIM);
            if (lane == 0) el_s[j] = e;
        }
        __syncthreads();

        if (tid == 0) {
            float e1 = -INFINITY, e2v = -INFINITY; int i1 = 0, i2 = 0;
            #pragma unroll
            for (int j = 0; j < EPG; ++j) {
                float v = el_s[j];
                if (v > e1)       { e2v = e1; i2 = i1; e1 = v; i1 = j; }
                else if (v > e2v) { e2v = v; i2 = j; }
            }
            float es = 0.f;
            #pragma unroll
            for (int j = 0; j < EPG; ++j) {
                float e = expf(el_s[j] - e1);
                rp_row[j] = e;
                es += e;
            }
            float inv = 1.f / es;
            float gp = s_gp;
            #pragma unroll
            for (int j = 0; j < EPG; ++j) rp_row[j] *= inv * gp;
            float v1 = expf(el_s[i1] - e1) * inv;
            float v2 = expf(el_s[i2] - e1) * inv;
            float u2 = s_u2;
            float denom = v1 + v2 * u2;
            s_n1 = v1 / denom; s_n2 = v2 * u2 / denom;
            s_e1 = gi * EPG + i1; s_e2 = gi * EPG + i2;
        }
        __syncthreads();

        if (tid < NE) {
            const int e = tid;
            float u2 = s_u2;
            float newD = (e == s_e1 ? 1.f : 0.f) + (e == s_e2 ? u2 : 0.f);
            float newC = (e == s_e1 ? s_n1 : 0.f) + (e == s_e2 ? s_n2 : 0.f);
            float newR = ((e >> 4) == gi) ? rp_row[e & 15] : 0.f;
            size_t ob = (size_t)tok * NE + e;
            float oldD = out[ob];
            float oldR = out[(size_t)2 * T_TOKENS * NE + ob];
            out[ob] = newD;
            out[(size_t)T_TOKENS * NE + ob] = newC;
            out[(size_t)2 * T_TOKENS * NE + ob] = newR;
            float dD = newD - oldD, dR = newR - oldR;
            if (dD != 0.f) atomicAdd(&sums[e], dD);
            if (dR != 0.f) atomicAdd(&sums[NE + e], dR);
        }
        __syncthreads();
    }
}

__global__ void moe_finalize(const float* __restrict__ sums, float* __restrict__ out) {
    int l = threadIdx.x;
    float v = sums[l] * sums[NE + l];
    #pragma unroll
    for (int off = 32; off; off >>= 1) v += __shfl_down(v, off, 64);
    if (l == 0) {
        float N = (float)T_TOKENS;
        out[(size_t)3 * T_TOKENS * NE] = v * (float)NE / (N * N);
    }
}

extern "C" void kernel_launch(void* const* d_in, const int* in_sizes, int n_in,
                              void* d_out, int out_size, void* d_ws, size_t ws_size,
                              hipStream_t stream) {
    const float* x  = (const float*)d_in[0];
    const float* Wg = (const float*)d_in[1];
    const float* We = (const float*)d_in[2];
    const float* W1 = (const float*)d_in[3];
    const float* b1 = (const float*)d_in[4];
    const float* W2 = (const float*)d_in[5];
    const float* b2 = (const float*)d_in[6];
    const int* minE = (const int*)d_in[7];
    const int* maxE = (const int*)d_in[8];
    float* out = (float*)d_out;
    float* ws  = (float*)d_ws;

    float* wfrag = ws;
    float* sums  = ws + SUM_OFF;
    int*   cnt   = (int*)(ws + CNT_OFF);
    int4*  list  = (int4*)(ws + LIST_OFF);

    moe_prep<<<64 * NT, 64, 0, stream>>>(Wg, We, W1, wfrag, sums, cnt);
    moe_fused<<<T_TOKENS / BM, 512, 0, stream>>>(x, wfrag, b1, W2, b2, minE, maxE,
                                                 out, sums, cnt, list);
    moe_fix<<<2048, 256, 0, stream>>>(x, Wg, We, W1, b1, W2, b2, minE, maxE,
                                      out, sums, cnt, list);
    moe_finalize<<<1, 64, 0, stream>>>(sums, out);
}